// Round 7
// baseline (178.242 us; speedup 1.0000x reference)
//
#include <hip/hip_runtime.h>
#include <hip/hip_bf16.h>
#include <hip/hip_fp16.h>

#define N_NODES 50000
#define N_EDGES 800000
// IN_F = 64, D_ATT = 64, HEADS = 8, D_HEAD = 8
// outputs: attention [E,8] | v [N,64] | prods [E,8]  (all fp32)

typedef __attribute__((ext_vector_type(4))) unsigned int uint4v;
typedef __attribute__((ext_vector_type(2))) float f32x2;
typedef __attribute__((ext_vector_type(4))) float f32x4;
typedef __attribute__((ext_vector_type(2))) int   i32x2;

static __device__ __forceinline__ float bfu_lo(unsigned int u) {
    union { unsigned int u; float f; } v; v.u = u << 16; return v.f;
}
static __device__ __forceinline__ float bfu_hi(unsigned int u) {
    union { unsigned int u; float f; } v; v.u = u & 0xffff0000u; return v.f;
}
static __device__ __forceinline__ unsigned short f2bf(float f) {
    union { float f; unsigned int u; } v; v.f = f;
    v.u += 0x7fffu + ((v.u >> 16) & 1u);  // RNE
    return (unsigned short)(v.u >> 16);
}

// ---------------------------------------------------------------------------
// Kernel 1: fused Q/K/V projection + ssum zeroing.
// R13 trim: 64-row blocks (782) -- each W-chunk VMEM load (L2-hit) now feeds
// 16 rows/wave instead of 8, halving the W re-read stream. Same FMA count.
// VGPR ~110 (48 acc + 24 W + x/addr), no spill at __launch_bounds__(256,2).
// Q/K stored d-major bf16 (gather rows = 128 B); V fp32 NT.
// ---------------------------------------------------------------------------
__global__ __launch_bounds__(256, 2)
void proj_qkv(const float* __restrict__ x,
              const float* __restrict__ Wq, const float* __restrict__ bq,
              const float* __restrict__ Wk, const float* __restrict__ bk,
              const float* __restrict__ Wv, const float* __restrict__ bv,
              unsigned short* __restrict__ Qb, unsigned short* __restrict__ Kb,
              float* __restrict__ V, unsigned int* __restrict__ ssum_u)
{
    __shared__ float xs[64 * 64];  // 16 KB
    const int tid  = threadIdx.x;
    const int c    = tid & 63;      // output column 0..63
    const int w    = tid >> 6;      // wave id 0..3
    const int row0 = blockIdx.x * 64;
    const int nrows = min(64, N_NODES - row0);

    // ssum zeroing: N_NODES*4 dwords = 200000 (grid 782*256 = 200192)
    {
        const int z = blockIdx.x * 256 + tid;
        if (z < N_NODES * 4) ssum_u[z] = 0u;
    }

    // stage x tile once (coalesced float4)
    {
        const float4* xg  = (const float4*)(x + (size_t)row0 * 64);
        float4*       xs4 = (float4*)xs;
        const int nf4 = nrows * 16;
        for (int i = tid; i < nf4; i += 256) xs4[i] = xg[i];
    }
    __syncthreads();

    const int r0 = w * 16;  // this wave's 16 rows

    float accq[16], acck[16], accv[16];
    {
        const float bqc = bq[c], bkc = bk[c], bvc = bv[c];
#pragma unroll
        for (int i = 0; i < 16; ++i) { accq[i] = bqc; acck[i] = bkc; accv[i] = bvc; }
    }

    for (int jc = 0; jc < 8; ++jc) {  // K-dim in chunks of 8
        float wq[8], wk[8], wv[8];    // L2-resident W re-reads (1x per 16 rows)
#pragma unroll
        for (int j = 0; j < 8; ++j) {
            const int row = (jc * 8 + j) * 64 + c;
            wq[j] = Wq[row]; wk[j] = Wk[row]; wv[j] = Wv[row];
        }
#pragma unroll
        for (int i = 0; i < 16; ++i) {
            const float4* xr = (const float4*)(xs + (r0 + i) * 64 + jc * 8);
            const float4 xv0 = xr[0], xv1 = xr[1];  // wave-uniform broadcast
            accq[i] += xv0.x * wq[0] + xv0.y * wq[1] + xv0.z * wq[2] + xv0.w * wq[3]
                     + xv1.x * wq[4] + xv1.y * wq[5] + xv1.z * wq[6] + xv1.w * wq[7];
            acck[i] += xv0.x * wk[0] + xv0.y * wk[1] + xv0.z * wk[2] + xv0.w * wk[3]
                     + xv1.x * wk[4] + xv1.y * wk[5] + xv1.z * wk[6] + xv1.w * wk[7];
            accv[i] += xv0.x * wv[0] + xv0.y * wv[1] + xv0.z * wv[2] + xv0.w * wv[3]
                     + xv1.x * wv[4] + xv1.y * wv[5] + xv1.z * wv[6] + xv1.w * wv[7];
        }
    }

    // d-major permutation for Q/K (within the 128B row segment) -> coalesced
    const int ocqk = (c & 7) * 8 + (c >> 3);
#pragma unroll
    for (int i = 0; i < 16; ++i) {
        const int r = r0 + i;
        if (r < nrows) {
            const size_t o = (size_t)(row0 + r) * 64;
            Qb[o + ocqk] = f2bf(accq[i]);
            Kb[o + ocqk] = f2bf(acck[i]);
            __builtin_nontemporal_store(accv[i], V + o + c);
        }
    }
}

// ---------------------------------------------------------------------------
// Kernel 2: EXACT R1 body (best verified). TWO edges per thread, 4 threads
// per edge d-slot; e-major ssum so the 4 dp lanes' pk-f16 atomics merge into
// ~1 fabric transaction/edge (R10: breaking this = 3.5x slower). Pinned at
// ~46.5 us across 4 structural variants -> at the device-atomic/fabric floor.
// Softmax max-shift skipped: |p| <= ~8, exp() safe in fp32; ratio identical.
// ---------------------------------------------------------------------------
__global__ __launch_bounds__(256)
void edge_kernel(const unsigned short* __restrict__ Qb,
                 const unsigned short* __restrict__ Kb,
                 const int* __restrict__ edge,
                 float* __restrict__ prods, __half2* __restrict__ ssum)
{
    const int gid = blockIdx.x * 256 + threadIdx.x;  // [0, N_EDGES*2) exact
    const int e2 = gid >> 2;           // edge-pair index
    const int dp = gid & 3;            // d pair index: d = 2dp, 2dp+1
    const int eA = e2 * 2;             // even edge; eB = eA+1

    const i32x2 esrc = *(const i32x2*)(edge + eA);
    const i32x2 edst = *(const i32x2*)(edge + N_EDGES + eA);

    // 8 independent 16B gathers in flight; lanes 0-3 cover one 128 B row
    const uint4v* qA = (const uint4v*)(Qb + (size_t)esrc.x * 64 + dp * 16);
    const uint4v* kA = (const uint4v*)(Kb + (size_t)edst.x * 64 + dp * 16);
    const uint4v* qB = (const uint4v*)(Qb + (size_t)esrc.y * 64 + dp * 16);
    const uint4v* kB = (const uint4v*)(Kb + (size_t)edst.y * 64 + dp * 16);
    const uint4v qA0 = qA[0], qA1 = qA[1];
    const uint4v kA0 = kA[0], kA1 = kA[1];
    const uint4v qB0 = qB[0], qB1 = qB[1];
    const uint4v kB0 = kB[0], kB1 = kB[1];

    float sA0 = 0.f, sA1 = 0.f, sB0 = 0.f, sB1 = 0.f;
#pragma unroll
    for (int i = 0; i < 4; ++i) {
        sA0 += bfu_lo(qA0[i]) * bfu_lo(kA0[i]) + bfu_hi(qA0[i]) * bfu_hi(kA0[i]);
        sA1 += bfu_lo(qA1[i]) * bfu_lo(kA1[i]) + bfu_hi(qA1[i]) * bfu_hi(kA1[i]);
        sB0 += bfu_lo(qB0[i]) * bfu_lo(kB0[i]) + bfu_hi(qB0[i]) * bfu_hi(kB0[i]);
        sB1 += bfu_lo(qB1[i]) * bfu_lo(kB1[i]) + bfu_hi(qB1[i]) * bfu_hi(kB1[i]);
    }

    const float cc = 0.35355339059327373f;  // 1/sqrt(8)
    const float pA0 = sA0 * cc, pA1 = sA1 * cc;
    const float pB0 = sB0 * cc, pB1 = sB1 * cc;
    *(f32x2*)(prods + (size_t)eA * 8 + dp * 2)       = (f32x2){pA0, pA1};
    *(f32x2*)(prods + (size_t)(eA + 1) * 8 + dp * 2) = (f32x2){pB0, pB1};
    // e-major ssum [node][4 half2]: dp lanes adjacent -> merged transaction
    unsafeAtomicAdd(ssum + (size_t)edst.x * 4 + dp,
                    __floats2half2_rn(__expf(pA0), __expf(pA1)));
    unsafeAtomicAdd(ssum + (size_t)edst.y * 4 + dp,
                    __floats2half2_rn(__expf(pB0), __expf(pB1)));
}

// ---------------------------------------------------------------------------
// Kernel 3: attention = exp(prods) / segment-sum.
// R13 trim: ONE edge per thread, 16-B vector ops -- half the threads, one
// 16-B ssum gather per edge (memory-identical to the old 4x4-B same-line
// lane loads, but 1/4 the load instructions), f32x4 NT att stores.
// Plain cached loads on prods/edge (R9: NT on re-read paths costs ~7 us).
// ---------------------------------------------------------------------------
__global__ __launch_bounds__(256)
void norm_kernel(const int* __restrict__ edge,
                 const float* __restrict__ prods,
                 const __half2* __restrict__ ssum, float* __restrict__ att)
{
    const int e = blockIdx.x * 256 + threadIdx.x;  // [0, 800000) exact
    const int dst = edge[N_EDGES + e];

    const f32x4 p01 = *(const f32x4*)(prods + (size_t)e * 8);
    const f32x4 p23 = *(const f32x4*)(prods + (size_t)e * 8 + 4);
    const uint4v sv = *(const uint4v*)(ssum + (size_t)dst * 4);  // 4x half2

    const __half2* sh = (const __half2*)&sv;
    f32x4 a0, a1;
    a0.x = __expf(p01.x) / (__low2float(sh[0])  + 1e-16f);
    a0.y = __expf(p01.y) / (__high2float(sh[0]) + 1e-16f);
    a0.z = __expf(p01.z) / (__low2float(sh[1])  + 1e-16f);
    a0.w = __expf(p01.w) / (__high2float(sh[1]) + 1e-16f);
    a1.x = __expf(p23.x) / (__low2float(sh[2])  + 1e-16f);
    a1.y = __expf(p23.y) / (__high2float(sh[2]) + 1e-16f);
    a1.z = __expf(p23.z) / (__low2float(sh[3])  + 1e-16f);
    a1.w = __expf(p23.w) / (__high2float(sh[3]) + 1e-16f);
    __builtin_nontemporal_store(a0, (f32x4*)(att + (size_t)e * 8));
    __builtin_nontemporal_store(a1, (f32x4*)(att + (size_t)e * 8 + 4));
}

extern "C" void kernel_launch(void* const* d_in, const int* in_sizes, int n_in,
                              void* d_out, int out_size, void* d_ws, size_t ws_size,
                              hipStream_t stream)
{
    const float* x    = (const float*)d_in[0];
    const float* Wq   = (const float*)d_in[1];
    const float* bq   = (const float*)d_in[2];
    const float* Wk   = (const float*)d_in[3];
    const float* bk   = (const float*)d_in[4];
    const float* Wv   = (const float*)d_in[5];
    const float* bv   = (const float*)d_in[6];
    const int*   edge = (const int*)d_in[7];

    float* out   = (float*)d_out;
    float* att   = out;                      // 6,400,000 floats
    float* V     = out + 6400000;            // 3,200,000 floats
    float* prods = out + 9600000;            // 6,400,000 floats

    unsigned short* Qb = (unsigned short*)d_ws;      // 3.2M ushort (d-major bf16)
    unsigned short* Kb = Qb + 3200000;               // 3.2M ushort
    __half2*        ssum = (__half2*)(Kb + 3200000); // 200,000 half2 (800 KB)

    proj_qkv<<<(N_NODES + 63) / 64, 256, 0, stream>>>(
        x, Wq, bq, Wk, bk, Wv, bv, Qb, Kb, V, (unsigned int*)ssum);

    // single edge dispatch (R12 split cost ~5 us of boundary overhead)
    const int nwork = N_EDGES * 2;
    edge_kernel<<<nwork / 256, 256, 0, stream>>>(Qb, Kb, edge, prods, ssum);

    norm_kernel<<<N_EDGES / 256, 256, 0, stream>>>(edge, prods, ssum, att);
}

// Round 8
// 170.504 us; speedup vs baseline: 1.0454x; 1.0454x over previous
//
#include <hip/hip_runtime.h>
#include <hip/hip_bf16.h>
#include <hip/hip_fp16.h>

#define N_NODES 50000
#define N_EDGES 800000
// IN_F = 64, D_ATT = 64, HEADS = 8, D_HEAD = 8
// outputs: attention [E,8] | v [N,64] | prods [E,8]  (all fp32)

typedef __attribute__((ext_vector_type(4))) unsigned int uint4v;
typedef __attribute__((ext_vector_type(2))) float f32x2;
typedef __attribute__((ext_vector_type(2))) int   i32x2;

static __device__ __forceinline__ float bfu_lo(unsigned int u) {
    union { unsigned int u; float f; } v; v.u = u << 16; return v.f;
}
static __device__ __forceinline__ float bfu_hi(unsigned int u) {
    union { unsigned int u; float f; } v; v.u = u & 0xffff0000u; return v.f;
}
static __device__ __forceinline__ unsigned short f2bf(float f) {
    union { float f; unsigned int u; } v; v.f = f;
    v.u += 0x7fffu + ((v.u >> 16) & 1u);  // RNE
    return (unsigned short)(v.u >> 16);
}

// ---------------------------------------------------------------------------
// R14: EXACT revert to the best-verified configuration (R1, 170.8 us).
// Session findings baked into this structure:
//  - proj 32-row blocks (R13: 64-row regressed; register pressure)
//  - edge: 2 edges/thread, 4 dp-lanes/edge, e-major tables+ssum so the
//    pk-f16 atomics of the 4 dp lanes merge to ~1 fabric transaction/edge
//    (R10: breaking this = 3.5x slower). Pinned at ~46 us across 5 variants
//    -> random-fabric transaction floor.
//  - norm: 2 edges/thread, cached prods/edge reads (R9: NT re-read -7 us),
//    NT att stores (R13: 1-edge variant regressed).
//  - 3 dispatches minimal (R11: coop fusion 558 us; R12: split +5 us).
// ---------------------------------------------------------------------------
__global__ __launch_bounds__(256, 2)
void proj_qkv(const float* __restrict__ x,
              const float* __restrict__ Wq, const float* __restrict__ bq,
              const float* __restrict__ Wk, const float* __restrict__ bk,
              const float* __restrict__ Wv, const float* __restrict__ bv,
              unsigned short* __restrict__ Qb, unsigned short* __restrict__ Kb,
              float* __restrict__ V, unsigned int* __restrict__ ssum_u)
{
    __shared__ float xs[32 * 64];  // 8 KB
    const int tid  = threadIdx.x;
    const int c    = tid & 63;      // output column 0..63
    const int w    = tid >> 6;      // wave id 0..3
    const int row0 = blockIdx.x * 32;
    const int nrows = min(32, N_NODES - row0);

    // ssum zeroing: N_NODES*8 halves = N_NODES*4 dwords (grid covers 400128)
    {
        const int z = blockIdx.x * 256 + tid;
        if (z < N_NODES * 4) ssum_u[z] = 0u;
    }

    // stage x tile once (coalesced float4)
    {
        const float4* xg  = (const float4*)(x + (size_t)row0 * 64);
        float4*       xs4 = (float4*)xs;
        const int nf4 = nrows * 16;
        for (int i = tid; i < nf4; i += 256) xs4[i] = xg[i];
    }
    __syncthreads();

    const int r0 = w * 8;  // this wave's 8 rows

    float accq[8], acck[8], accv[8];
    {
        const float bqc = bq[c], bkc = bk[c], bvc = bv[c];
#pragma unroll
        for (int i = 0; i < 8; ++i) { accq[i] = bqc; acck[i] = bkc; accv[i] = bvc; }
    }

    for (int jc = 0; jc < 8; ++jc) {  // K-dim in chunks of 8
        float wq[8], wk[8], wv[8];    // L2-resident W re-reads
#pragma unroll
        for (int j = 0; j < 8; ++j) {
            const int row = (jc * 8 + j) * 64 + c;
            wq[j] = Wq[row]; wk[j] = Wk[row]; wv[j] = Wv[row];
        }
#pragma unroll
        for (int i = 0; i < 8; ++i) {
            const float4* xr = (const float4*)(xs + (r0 + i) * 64 + jc * 8);
            const float4 xv0 = xr[0], xv1 = xr[1];  // wave-uniform broadcast
            accq[i] += xv0.x * wq[0] + xv0.y * wq[1] + xv0.z * wq[2] + xv0.w * wq[3]
                     + xv1.x * wq[4] + xv1.y * wq[5] + xv1.z * wq[6] + xv1.w * wq[7];
            acck[i] += xv0.x * wk[0] + xv0.y * wk[1] + xv0.z * wk[2] + xv0.w * wk[3]
                     + xv1.x * wk[4] + xv1.y * wk[5] + xv1.z * wk[6] + xv1.w * wk[7];
            accv[i] += xv0.x * wv[0] + xv0.y * wv[1] + xv0.z * wv[2] + xv0.w * wv[3]
                     + xv1.x * wv[4] + xv1.y * wv[5] + xv1.z * wv[6] + xv1.w * wv[7];
        }
    }

    // d-major permutation for Q/K (within the 128B row segment) -> coalesced
    const int ocqk = (c & 7) * 8 + (c >> 3);
#pragma unroll
    for (int i = 0; i < 8; ++i) {
        const int r = r0 + i;
        if (r < nrows) {
            const size_t o = (size_t)(row0 + r) * 64;
            Qb[o + ocqk] = f2bf(accq[i]);
            Kb[o + ocqk] = f2bf(acck[i]);
            __builtin_nontemporal_store(accv[i], V + o + c);
        }
    }
}

__global__ __launch_bounds__(256)
void edge_kernel(const unsigned short* __restrict__ Qb,
                 const unsigned short* __restrict__ Kb,
                 const int* __restrict__ edge,
                 float* __restrict__ prods, __half2* __restrict__ ssum)
{
    const int gid = blockIdx.x * 256 + threadIdx.x;  // [0, N_EDGES*2) exact
    const int e2 = gid >> 2;           // edge-pair index
    const int dp = gid & 3;            // d pair index: d = 2dp, 2dp+1
    const int eA = e2 * 2;             // even edge; eB = eA+1

    const i32x2 esrc = *(const i32x2*)(edge + eA);
    const i32x2 edst = *(const i32x2*)(edge + N_EDGES + eA);

    // 8 independent 16B gathers in flight; lanes 0-3 cover one 128 B row
    const uint4v* qA = (const uint4v*)(Qb + (size_t)esrc.x * 64 + dp * 16);
    const uint4v* kA = (const uint4v*)(Kb + (size_t)edst.x * 64 + dp * 16);
    const uint4v* qB = (const uint4v*)(Qb + (size_t)esrc.y * 64 + dp * 16);
    const uint4v* kB = (const uint4v*)(Kb + (size_t)edst.y * 64 + dp * 16);
    const uint4v qA0 = qA[0], qA1 = qA[1];
    const uint4v kA0 = kA[0], kA1 = kA[1];
    const uint4v qB0 = qB[0], qB1 = qB[1];
    const uint4v kB0 = kB[0], kB1 = kB[1];

    float sA0 = 0.f, sA1 = 0.f, sB0 = 0.f, sB1 = 0.f;
#pragma unroll
    for (int i = 0; i < 4; ++i) {
        sA0 += bfu_lo(qA0[i]) * bfu_lo(kA0[i]) + bfu_hi(qA0[i]) * bfu_hi(kA0[i]);
        sA1 += bfu_lo(qA1[i]) * bfu_lo(kA1[i]) + bfu_hi(qA1[i]) * bfu_hi(kA1[i]);
        sB0 += bfu_lo(qB0[i]) * bfu_lo(kB0[i]) + bfu_hi(qB0[i]) * bfu_hi(kB0[i]);
        sB1 += bfu_lo(qB1[i]) * bfu_lo(kB1[i]) + bfu_hi(qB1[i]) * bfu_hi(kB1[i]);
    }

    const float cc = 0.35355339059327373f;  // 1/sqrt(8)
    const float pA0 = sA0 * cc, pA1 = sA1 * cc;
    const float pB0 = sB0 * cc, pB1 = sB1 * cc;
    *(f32x2*)(prods + (size_t)eA * 8 + dp * 2)       = (f32x2){pA0, pA1};
    *(f32x2*)(prods + (size_t)(eA + 1) * 8 + dp * 2) = (f32x2){pB0, pB1};
    // e-major ssum [node][4 half2]: dp lanes adjacent -> merged transaction
    unsafeAtomicAdd(ssum + (size_t)edst.x * 4 + dp,
                    __floats2half2_rn(__expf(pA0), __expf(pA1)));
    unsafeAtomicAdd(ssum + (size_t)edst.y * 4 + dp,
                    __floats2half2_rn(__expf(pB0), __expf(pB1)));
}

__global__ __launch_bounds__(256)
void norm_kernel(const int* __restrict__ edge,
                 const float* __restrict__ prods,
                 const __half2* __restrict__ ssum, float* __restrict__ att)
{
    const int gid = blockIdx.x * 256 + threadIdx.x;  // [0, N_EDGES*2) exact
    const int e2 = gid >> 2;
    const int dp = gid & 3;
    const int eA = e2 * 2;

    const i32x2 edst = *(const i32x2*)(edge + N_EDGES + eA);

    const f32x2 pA = *(const f32x2*)(prods + (size_t)eA * 8 + dp * 2);
    const f32x2 pB = *(const f32x2*)(prods + (size_t)(eA + 1) * 8 + dp * 2);
    const __half2 sA = ssum[(size_t)edst.x * 4 + dp];
    const __half2 sB = ssum[(size_t)edst.y * 4 + dp];

    f32x2 rA, rB;
    rA.x = __expf(pA.x) / (__low2float(sA)  + 1e-16f);
    rA.y = __expf(pA.y) / (__high2float(sA) + 1e-16f);
    rB.x = __expf(pB.x) / (__low2float(sB)  + 1e-16f);
    rB.y = __expf(pB.y) / (__high2float(sB) + 1e-16f);
    __builtin_nontemporal_store(rA, (f32x2*)(att + (size_t)eA * 8 + dp * 2));
    __builtin_nontemporal_store(rB, (f32x2*)(att + (size_t)(eA + 1) * 8 + dp * 2));
}

extern "C" void kernel_launch(void* const* d_in, const int* in_sizes, int n_in,
                              void* d_out, int out_size, void* d_ws, size_t ws_size,
                              hipStream_t stream)
{
    const float* x    = (const float*)d_in[0];
    const float* Wq   = (const float*)d_in[1];
    const float* bq   = (const float*)d_in[2];
    const float* Wk   = (const float*)d_in[3];
    const float* bk   = (const float*)d_in[4];
    const float* Wv   = (const float*)d_in[5];
    const float* bv   = (const float*)d_in[6];
    const int*   edge = (const int*)d_in[7];

    float* out   = (float*)d_out;
    float* att   = out;                      // 6,400,000 floats
    float* V     = out + 6400000;            // 3,200,000 floats
    float* prods = out + 9600000;            // 6,400,000 floats

    unsigned short* Qb = (unsigned short*)d_ws;      // 3.2M ushort (d-major bf16)
    unsigned short* Kb = Qb + 3200000;               // 3.2M ushort
    __half2*        ssum = (__half2*)(Kb + 3200000); // 200,000 half2 (800 KB)

    proj_qkv<<<(N_NODES + 31) / 32, 256, 0, stream>>>(
        x, Wq, bq, Wk, bk, Wv, bv, Qb, Kb, V, (unsigned int*)ssum);

    const int nwork = N_EDGES * 2;
    edge_kernel<<<nwork / 256, 256, 0, stream>>>(Qb, Kb, edge, prods, ssum);
    norm_kernel<<<nwork / 256, 256, 0, stream>>>(edge, prods, ssum, att);
}